// Round 9
// baseline (121.037 us; speedup 1.0000x reference)
//
#include <hip/hip_runtime.h>

constexpr int B = 64;
constexpr int N = 8192;
constexpr int D = 256;
constexpr int K = 128;
constexpr int CHUNKS = 32;                 // chunks per batch
constexpr int RPC = N / CHUNKS;            // 256 rows per chunk (per block)
constexpr int NCAND = CHUNKS * K;          // 4096 candidates per batch

typedef unsigned long long ull;

__device__ __forceinline__ int bitrev6(int l) {
    return ((l & 1) << 5) | ((l & 2) << 3) | ((l & 4) << 1)
         | ((l & 8) >> 1) | ((l & 16) >> 3) | ((l & 32) >> 5);
}

// --- Stage 1: norm + local top-K, barrier-free wave-private reduction -------
// 2048 blocks x 256 threads; wave w owns rows [w*64, w*64+64) of its chunk,
// processed as 4 groups of 16 rows in a PRIVATE LDS region part[w] -- no
// __syncthreads in the streaming loop (round-8 had 8 block barriers + a
// single-wave phase-2; waves stalled on each other). Wave-local DS ordering
// is handled by compiler-inserted lgkmcnt.
//
// BIT-EXACTNESS (same as round 8): lane partial x*x+y*y+z*z+w*w written at
// column bitrev6(lane); balanced-tree fold over columns 0..63 == rounds-1-4
// butterfly bitwise. Keys bit-identical -> selection provably unchanged.
// part stride 68 floats = 272 B (16B-multiple): ds_read_b128-aligned, and
// write banks (brl perm) / read banks (4r+4j) are <=2-way aliased = free.
__global__ __launch_bounds__(256) void norm_select_kernel(const float* __restrict__ x,
                                                          ull* __restrict__ cand) {
    __shared__ __attribute__((aligned(16))) float part[4][16][68];  // 17.4 KiB
    __shared__ ull skeys[RPC];                                      // 2 KiB
    const int bid   = blockIdx.x;
    const int batch = bid >> 5;                   // / CHUNKS
    const int chunk = bid & (CHUNKS - 1);
    const int tid   = threadIdx.x;
    const int w     = tid >> 6;
    const int lane  = tid & 63;
    const int brl   = bitrev6(lane);
    const size_t rowbase = (size_t)batch * N + (size_t)chunk * RPC;
    const float* wbase = x + (rowbase + (size_t)w * 64) * D;

    for (int g = 0; g < 4; ++g) {                 // 16 rows per group
        #pragma unroll
        for (int it0 = 0; it0 < 16; it0 += 4) {
            float4 v[4];
            #pragma unroll
            for (int u = 0; u < 4; ++u)
                v[u] = reinterpret_cast<const float4*>(
                           wbase + (size_t)(g * 16 + it0 + u) * D)[lane];
            #pragma unroll
            for (int u = 0; u < 4; ++u)
                part[w][it0 + u][brl] = v[u].x * v[u].x + v[u].y * v[u].y
                                      + v[u].z * v[u].z + v[u].w * v[u].w;
        }
        // Wave-local reduce: lane r<16 folds row r of this group (b128 reads).
        if (lane < 16) {
            const float4* rowp = reinterpret_cast<const float4*>(&part[w][lane][0]);
            float gg[8];
            #pragma unroll
            for (int grp = 0; grp < 8; ++grp) {
                const float4 qa = rowp[grp * 2];
                const float4 qb = rowp[grp * 2 + 1];
                gg[grp] = ((qa.x + qa.y) + (qa.z + qa.w))
                        + ((qb.x + qb.y) + (qb.z + qb.w));
            }
            const float s = ((gg[0] + gg[1]) + (gg[2] + gg[3]))
                          + ((gg[4] + gg[5]) + (gg[6] + gg[7]));
            const int lrow = w * 64 + g * 16 + lane;          // row in chunk
            const int grow = chunk * RPC + lrow;              // row in batch
            skeys[lrow] = ((ull)__float_as_uint(s) << 32)
                        | (unsigned int)(N - 1 - grow);       // stable tie-break
        }
    }
    __syncthreads();                              // only barrier: skeys ready

    // All-pairs rank among 256 distinct keys (broadcast LDS reads);
    // top 128 write themselves to their exact rank slot (sorted, no atomics).
    const ull mine = skeys[tid];
    int rank = 0;
    for (int j = 0; j < RPC; ++j)
        rank += (skeys[j] > mine) ? 1 : 0;
    if (rank < K)
        cand[(size_t)bid * K + rank] = mine;
}

// --- Stage 2: exact top-K select over 4096 candidates (indices only) --------
// One 1024-thread block per batch; radix select identical to rounds 4-8.
// Gather moved to its own full-grid kernel (it was funneling 16 MiB through
// 64 CUs ~= 10us; full-chip it is ~3us).
__global__ __launch_bounds__(1024) void topk_select_kernel(const ull* __restrict__ cand_in,
                                                           int* __restrict__ idx_out) {
    __shared__ ull keys[NCAND];                   // 32 KiB
    __shared__ unsigned int hist[256];
    __shared__ unsigned int seg[32];
    __shared__ ull s_prefix;
    __shared__ unsigned int s_krem;
    __shared__ int s_done;
    __shared__ unsigned int s_cnt;
    __shared__ ull sel[K];

    const int b    = blockIdx.x;
    const int tid  = threadIdx.x;
    const int lane = tid & 63;

    for (int i = tid; i < NCAND; i += 1024)
        keys[i] = cand_in[(size_t)b * NCAND + i];
    if (tid == 0) { s_prefix = 0ull; s_krem = K; s_done = 0; s_cnt = 0u; }
    __syncthreads();

    for (int p = 7; p >= 0; --p) {
        if (s_done) break;                         // uniform, barrier-separated
        const int shift = p * 8;
        const ull          prefix = s_prefix;
        const unsigned int krem   = s_krem;
        if (tid < 256) hist[tid] = 0u;
        __syncthreads();

        if (p == 7) {
            // Digits heavily duplicated: ballot-aggregated atomics.
            for (int i = tid; i < NCAND; i += 1024) {
                const unsigned int d = (unsigned int)(keys[i] >> 56);
                ull rem = __ballot(true);
                while (rem) {
                    const int leader = __ffsll(rem) - 1;
                    const unsigned int dl = __shfl(d, leader, 64);
                    const ull grp = __ballot(d == dl);
                    if (lane == leader) atomicAdd(&hist[dl], (unsigned int)__popcll(grp));
                    rem &= ~grp;
                }
            }
        } else {
            for (int i = tid; i < NCAND; i += 1024) {
                const ull key = keys[i];
                if ((key >> (shift + 8)) == (prefix >> (shift + 8)))
                    atomicAdd(&hist[(unsigned int)(key >> shift) & 255u], 1u);
            }
        }
        __syncthreads();

        if (tid < 32) {                            // segment sums of 8 bins
            unsigned int s = 0;
            #pragma unroll
            for (int d2 = 0; d2 < 8; ++d2) s += hist[tid * 8 + d2];
            seg[tid] = s;
        }
        __syncthreads();

        if (tid < 256) {
            unsigned int cnt_gt = 0;
            const int hiSeg = (tid >> 3) + 1;
            for (int s2 = hiSeg; s2 < 32; ++s2) cnt_gt += seg[s2];
            for (int d2 = tid + 1; d2 < hiSeg * 8; ++d2) cnt_gt += hist[d2];
            const unsigned int h = hist[tid];
            if (cnt_gt < krem && krem <= cnt_gt + h) {   // unique winner
                s_prefix = prefix | ((ull)tid << shift);
                s_krem   = krem - cnt_gt;
                if (h == krem - cnt_gt) s_done = 1;
            }
        }
        __syncthreads();
    }

    const ull T = s_prefix;
    for (int i = tid; i < NCAND; i += 1024) {
        const ull key = keys[i];
        if (key >= T) {
            const unsigned int pos = atomicAdd(&s_cnt, 1u);
            sel[pos] = key;
        }
    }
    __syncthreads();

    // Rank by all-pairs compare; write row index at its output rank.
    if (tid < K) {
        const ull key = sel[tid];
        int rank = 0;
        for (int j = 0; j < K; ++j) rank += (sel[j] > key) ? 1 : 0;
        idx_out[b * K + rank] = N - 1 - (int)(key & 0xFFFFFFFFu);
    }
}

// --- Stage 3: full-grid gather ----------------------------------------------
// 2048 blocks x 256 threads; wave per output row, float4 per lane (1 KiB).
__global__ __launch_bounds__(256) void gather_kernel(const float* __restrict__ x,
                                                     const int* __restrict__ idx,
                                                     float* __restrict__ out) {
    const int row  = blockIdx.x * 4 + (threadIdx.x >> 6);    // 0 .. B*K-1
    const int lane = threadIdx.x & 63;
    const int b    = row >> 7;                                // / K
    const int src  = idx[row];
    const float4 v = reinterpret_cast<const float4*>(x + ((size_t)b * N + src) * D)[lane];
    reinterpret_cast<float4*>(out + (size_t)row * D)[lane] = v;
}

extern "C" void kernel_launch(void* const* d_in, const int* in_sizes, int n_in,
                              void* d_out, int out_size, void* d_ws, size_t ws_size,
                              hipStream_t stream) {
    const float* x = (const float*)d_in[0];
    float* out = (float*)d_out;
    ull* cand = (ull*)d_ws;                        // B*NCAND u64 = 2 MiB
    int* idx  = (int*)(cand + (size_t)B * NCAND);  // B*K int = 32 KiB

    norm_select_kernel<<<B * CHUNKS, 256, 0, stream>>>(x, cand);
    topk_select_kernel<<<B, 1024, 0, stream>>>(cand, idx);
    gather_kernel<<<B * K / 4, 256, 0, stream>>>(x, idx, out);
}

// Round 10
// 114.923 us; speedup vs baseline: 1.0532x; 1.0532x over previous
//
#include <hip/hip_runtime.h>

constexpr int B = 64;
constexpr int N = 8192;
constexpr int D = 256;
constexpr int K = 128;
constexpr int CHUNKS = 32;                 // chunks per batch
constexpr int RPC = N / CHUNKS;            // 256 rows per chunk (per block)
constexpr int NCAND = CHUNKS * K;          // 4096 candidates per batch
constexpr int TILE = 64;                   // rows per LDS tile (4 tiles/block)

typedef unsigned long long ull;

__device__ __forceinline__ int bitrev6(int l) {
    return ((l & 1) << 5) | ((l & 2) << 3) | ((l & 4) << 1)
         | ((l & 8) >> 1) | ((l & 16) >> 3) | ((l & 32) >> 5);
}

// --- Stage 1: norm + local top-K (BYTE-IDENTICAL to round 8, best measured) -
// Hot loop: load -> 4 VALU -> ds_write at column bitrev6(lane); block-barrier
// phase-2 folds 64 partials per row as the standard balanced tree ==
// rounds-1-4 butterfly bitwise (FP add commutativity) -> keys bit-identical,
// selection provably unchanged. Round-9's wave-private variant regressed
// ~10us (per-16-row lgkmcnt drain on the critical path) - reverted.
__global__ __launch_bounds__(256) void norm_select_kernel(const float* __restrict__ x,
                                                          ull* __restrict__ cand) {
    __shared__ float part[TILE][65];              // 16.6 KiB, stride-65 pad
    __shared__ ull skeys[RPC];                    // 2 KiB
    const int bid   = blockIdx.x;
    const int batch = bid >> 5;                   // / CHUNKS
    const int chunk = bid & (CHUNKS - 1);
    const int tid   = threadIdx.x;
    const int w     = tid >> 6;
    const int lane  = tid & 63;
    const int brl   = bitrev6(lane);
    const size_t rowbase = (size_t)batch * N + (size_t)chunk * RPC;

    for (int tile = 0; tile < 4; ++tile) {
        // Wave w streams its 16 rows of this tile: load->VALU->ds_write only.
        const int r0 = w * 16;                    // wave's first row in tile
        const float* wbase = x + (rowbase + (size_t)(tile * TILE + r0)) * D;
        #pragma unroll
        for (int it0 = 0; it0 < 16; it0 += 4) {
            float4 v[4];
            #pragma unroll
            for (int u = 0; u < 4; ++u)
                v[u] = reinterpret_cast<const float4*>(wbase + (size_t)(it0 + u) * D)[lane];
            #pragma unroll
            for (int u = 0; u < 4; ++u)
                part[r0 + it0 + u][brl] = v[u].x * v[u].x + v[u].y * v[u].y
                                        + v[u].z * v[u].z + v[u].w * v[u].w;
        }
        __syncthreads();

        // Phase 2: thread t (<64) folds row t's 64 partials as the standard
        // balanced tree (== butterfly bits). Reads stride-65: conflict-free.
        if (tid < TILE) {
            float q[8];
            float g[8];
            #pragma unroll
            for (int grp = 0; grp < 8; ++grp) {
                #pragma unroll
                for (int j = 0; j < 8; ++j) q[j] = part[tid][grp * 8 + j];
                g[grp] = ((q[0] + q[1]) + (q[2] + q[3]))
                       + ((q[4] + q[5]) + (q[6] + q[7]));
            }
            const float s = ((g[0] + g[1]) + (g[2] + g[3]))
                          + ((g[4] + g[5]) + (g[6] + g[7]));
            const int grow = chunk * RPC + tile * TILE + tid;   // row in batch
            skeys[tile * TILE + tid] = ((ull)__float_as_uint(s) << 32)
                                     | (unsigned int)(N - 1 - grow);
        }
        __syncthreads();                          // part[] reused next tile
    }

    // All-pairs rank among 256 distinct keys (broadcast LDS reads);
    // top 128 write themselves to their exact rank slot (sorted, no atomics).
    const ull mine = skeys[tid];
    int rank = 0;
    for (int j = 0; j < RPC; ++j)
        rank += (skeys[j] > mine) ? 1 : 0;
    if (rank < K)
        cand[(size_t)bid * K + rank] = mine;
}

// --- Stage 2: exact top-K select over 4096 candidates (indices only) --------
// (BYTE-IDENTICAL to round 9.) One 1024-thread block per batch; radix select.
__global__ __launch_bounds__(1024) void topk_select_kernel(const ull* __restrict__ cand_in,
                                                           int* __restrict__ idx_out) {
    __shared__ ull keys[NCAND];                   // 32 KiB
    __shared__ unsigned int hist[256];
    __shared__ unsigned int seg[32];
    __shared__ ull s_prefix;
    __shared__ unsigned int s_krem;
    __shared__ int s_done;
    __shared__ unsigned int s_cnt;
    __shared__ ull sel[K];

    const int b    = blockIdx.x;
    const int tid  = threadIdx.x;
    const int lane = tid & 63;

    for (int i = tid; i < NCAND; i += 1024)
        keys[i] = cand_in[(size_t)b * NCAND + i];
    if (tid == 0) { s_prefix = 0ull; s_krem = K; s_done = 0; s_cnt = 0u; }
    __syncthreads();

    for (int p = 7; p >= 0; --p) {
        if (s_done) break;                         // uniform, barrier-separated
        const int shift = p * 8;
        const ull          prefix = s_prefix;
        const unsigned int krem   = s_krem;
        if (tid < 256) hist[tid] = 0u;
        __syncthreads();

        if (p == 7) {
            // Digits heavily duplicated: ballot-aggregated atomics.
            for (int i = tid; i < NCAND; i += 1024) {
                const unsigned int d = (unsigned int)(keys[i] >> 56);
                ull rem = __ballot(true);
                while (rem) {
                    const int leader = __ffsll(rem) - 1;
                    const unsigned int dl = __shfl(d, leader, 64);
                    const ull grp = __ballot(d == dl);
                    if (lane == leader) atomicAdd(&hist[dl], (unsigned int)__popcll(grp));
                    rem &= ~grp;
                }
            }
        } else {
            for (int i = tid; i < NCAND; i += 1024) {
                const ull key = keys[i];
                if ((key >> (shift + 8)) == (prefix >> (shift + 8)))
                    atomicAdd(&hist[(unsigned int)(key >> shift) & 255u], 1u);
            }
        }
        __syncthreads();

        if (tid < 32) {                            // segment sums of 8 bins
            unsigned int s = 0;
            #pragma unroll
            for (int d2 = 0; d2 < 8; ++d2) s += hist[tid * 8 + d2];
            seg[tid] = s;
        }
        __syncthreads();

        if (tid < 256) {
            unsigned int cnt_gt = 0;
            const int hiSeg = (tid >> 3) + 1;
            for (int s2 = hiSeg; s2 < 32; ++s2) cnt_gt += seg[s2];
            for (int d2 = tid + 1; d2 < hiSeg * 8; ++d2) cnt_gt += hist[d2];
            const unsigned int h = hist[tid];
            if (cnt_gt < krem && krem <= cnt_gt + h) {   // unique winner
                s_prefix = prefix | ((ull)tid << shift);
                s_krem   = krem - cnt_gt;
                if (h == krem - cnt_gt) s_done = 1;
            }
        }
        __syncthreads();
    }

    const ull T = s_prefix;
    for (int i = tid; i < NCAND; i += 1024) {
        const ull key = keys[i];
        if (key >= T) {
            const unsigned int pos = atomicAdd(&s_cnt, 1u);
            sel[pos] = key;
        }
    }
    __syncthreads();

    // Rank by all-pairs compare; write row index at its output rank.
    if (tid < K) {
        const ull key = sel[tid];
        int rank = 0;
        for (int j = 0; j < K; ++j) rank += (sel[j] > key) ? 1 : 0;
        idx_out[b * K + rank] = N - 1 - (int)(key & 0xFFFFFFFFu);
    }
}

// --- Stage 3: full-grid gather (BYTE-IDENTICAL to round 9) ------------------
// 2048 blocks x 256 threads; wave per output row, float4 per lane (1 KiB).
__global__ __launch_bounds__(256) void gather_kernel(const float* __restrict__ x,
                                                     const int* __restrict__ idx,
                                                     float* __restrict__ out) {
    const int row  = blockIdx.x * 4 + (threadIdx.x >> 6);    // 0 .. B*K-1
    const int lane = threadIdx.x & 63;
    const int b    = row >> 7;                                // / K
    const int src  = idx[row];
    const float4 v = reinterpret_cast<const float4*>(x + ((size_t)b * N + src) * D)[lane];
    reinterpret_cast<float4*>(out + (size_t)row * D)[lane] = v;
}

extern "C" void kernel_launch(void* const* d_in, const int* in_sizes, int n_in,
                              void* d_out, int out_size, void* d_ws, size_t ws_size,
                              hipStream_t stream) {
    const float* x = (const float*)d_in[0];
    float* out = (float*)d_out;
    ull* cand = (ull*)d_ws;                        // B*NCAND u64 = 2 MiB
    int* idx  = (int*)(cand + (size_t)B * NCAND);  // B*K int = 32 KiB

    norm_select_kernel<<<B * CHUNKS, 256, 0, stream>>>(x, cand);
    topk_select_kernel<<<B, 1024, 0, stream>>>(cand, idx);
    gather_kernel<<<B * K / 4, 256, 0, stream>>>(x, idx, out);
}